// Round 1
// baseline (33743.542 us; speedup 1.0000x reference)
//
#include <hip/hip_runtime.h>
#include <hip/hip_bf16.h>
#include <math.h>

#define T_STEPS 8192
#define NN      1024
#define KWG     32      // persistent workgroups in recurrent kernel
#define WCOLS   32      // NN / KWG columns owned per WG
#define RTHREADS 512

// ---------------- GEMM: C[8192,1024] = A[8192,1024] @ W[1024,1024] + bias ----
__global__ __launch_bounds__(256) void gemm_bias(
    const float* __restrict__ A, const float* __restrict__ W,
    const float* __restrict__ bias, float* __restrict__ C)
{
    const int bn = blockIdx.x;   // 0..15 (N tiles of 64)
    const int bm = blockIdx.y;   // 0..127 (M tiles of 64)
    const int tid = threadIdx.x;

    __shared__ float As[16][64];
    __shared__ float Bs[16][64];

    const int row0 = bm * 64, col0 = bn * 64;
    const int tm = (tid >> 4) << 2;   // 0..60
    const int tn = (tid & 15) << 2;   // 0..60

    float acc[4][4] = {};

    for (int k0 = 0; k0 < 1024; k0 += 16) {
        // A tile: 64 rows x 16 k, each thread loads a float4
        {
            const int m = tid >> 2, kq = (tid & 3) << 2;
            const float4 v = *reinterpret_cast<const float4*>(&A[(size_t)(row0 + m) * 1024 + k0 + kq]);
            As[kq + 0][m] = v.x; As[kq + 1][m] = v.y; As[kq + 2][m] = v.z; As[kq + 3][m] = v.w;
            const int kk = tid >> 4, nq = (tid & 15) << 2;
            *reinterpret_cast<float4*>(&Bs[kk][nq]) =
                *reinterpret_cast<const float4*>(&W[(size_t)(k0 + kk) * 1024 + col0 + nq]);
        }
        __syncthreads();
#pragma unroll
        for (int k = 0; k < 16; ++k) {
            const float4 a4 = *reinterpret_cast<const float4*>(&As[k][tm]);
            const float4 b4 = *reinterpret_cast<const float4*>(&Bs[k][tn]);
            const float a[4] = {a4.x, a4.y, a4.z, a4.w};
            const float b[4] = {b4.x, b4.y, b4.z, b4.w};
#pragma unroll
            for (int i = 0; i < 4; ++i)
#pragma unroll
                for (int j = 0; j < 4; ++j) acc[i][j] += a[i] * b[j];
        }
        __syncthreads();
    }
#pragma unroll
    for (int i = 0; i < 4; ++i)
#pragma unroll
        for (int j = 0; j < 4; ++j)
            C[(size_t)(row0 + tm + i) * 1024 + col0 + tn + j] = acc[i][j] + bias[col0 + tn + j];
}

// ---------------- Recurrent scan: 32 persistent WGs, weights in VGPRs --------
// Per step for WG g owning cols S=[g*32,(g+1)*32):
//   r_j   = sigmoid(xR[t,j] + sum_i h[i]*hRW[i,j] + hRB[j])        (local)
//   p[n] += sum_{j in S} (r_j*h[j]) * hW[j,n]  for all n           (rank-32)
//   exchange p via LLC slots (one comm round/step), everyone recomputes
//   h_new[n] = tanh(xT[t,n] + sum_g p_g[n] + hB[n]) redundantly.
__global__ __launch_bounds__(RTHREADS, 2) void gru_rec(
    const float* __restrict__ xT, const float* __restrict__ xR,
    const float* __restrict__ hRW, const float* __restrict__ hW,
    const float* __restrict__ hRB, const float* __restrict__ hB,
    const float* __restrict__ h0, float* __restrict__ out,
    float* __restrict__ slots,          // [2][KWG][NN]
    unsigned int* __restrict__ flags)   // [KWG * 16] (64B-padded counters)
{
    const int g = blockIdx.x;        // 0..31
    const int tid = threadIdx.x;     // 0..511
    const int lane = tid & 63;
    const int wave = tid >> 6;       // 0..7

    __shared__ float hsh[NN];
    __shared__ float part[16][WCOLS];
    __shared__ float rh[WCOLS];

    // phase 1 mapping: column j1 = tid&31, i-chunk sub = tid>>5 (64 i each)
    const int j1 = tid & (WCOLS - 1);
    const int sub = tid >> 5;        // 0..15
    float w1[64];
#pragma unroll
    for (int k = 0; k < 64; ++k)
        w1[k] = hRW[(size_t)(sub * 64 + k) * NN + g * WCOLS + j1];

    // phase 2 mapping: thread owns outputs n0 = tid, n1 = tid+512
    const int n0 = tid, n1 = tid + RTHREADS;
    float w2a[32], w2b[32];
#pragma unroll
    for (int k = 0; k < 32; ++k) {
        w2a[k] = hW[(size_t)(g * WCOLS + k) * NN + n0];
        w2b[k] = hW[(size_t)(g * WCOLS + k) * NN + n1];
    }

    const float hB0 = hB[n0], hB1 = hB[n1];
    float hRBj = 0.f;
    if (wave == 0 && lane < WCOLS) hRBj = hRB[g * WCOLS + lane];

    hsh[n0] = h0[n0];
    hsh[n1] = h0[n1];
    __syncthreads();

    for (int t = 0; t < T_STEPS; ++t) {
        // prefetch input-projection rows (consumed late in the step)
        const float xt0 = xT[(size_t)t * NN + n0];
        const float xt1 = xT[(size_t)t * NN + n1];
        const float xr = (wave == 0 && lane < WCOLS) ? xR[(size_t)t * NN + g * WCOLS + lane] : 0.f;

        // ---- phase 1: partial dots for r over i in [sub*64, sub*64+64)
        float a0 = 0.f, a1 = 0.f, a2 = 0.f, a3 = 0.f;
#pragma unroll
        for (int k = 0; k < 64; k += 4) {
            const float4 hv = *reinterpret_cast<const float4*>(&hsh[sub * 64 + k]);
            a0 += hv.x * w1[k + 0];
            a1 += hv.y * w1[k + 1];
            a2 += hv.z * w1[k + 2];
            a3 += hv.w * w1[k + 3];
        }
        part[sub][j1] = (a0 + a1) + (a2 + a3);
        __syncthreads();

        // ---- reduce 16 partials per column, sigmoid, r*h (wave 0)
        if (wave == 0) {
            const int jj = lane & 31;
            const int sh = lane >> 5;    // 0/1 splits the 16 partials
            float s = 0.f;
#pragma unroll
            for (int q = 0; q < 8; ++q) s += part[sh * 8 + q][jj];
            s += __shfl_xor(s, 32);
            if (lane < WCOLS) {
                const float z = xr + hRBj + s;
                const float r = 1.f / (1.f + expf(-z));
                rh[lane] = r * hsh[g * WCOLS + lane];
            }
        }
        __syncthreads();

        // ---- phase 2: rank-32 update, outputs n0 and n1
        float b0 = 0.f, b1 = 0.f, c0 = 0.f, c1 = 0.f;
#pragma unroll
        for (int k = 0; k < 32; k += 2) {
            const float2 rv = *reinterpret_cast<const float2*>(&rh[k]);
            b0 += rv.x * w2a[k];  b1 += rv.y * w2a[k + 1];
            c0 += rv.x * w2b[k];  c1 += rv.y * w2b[k + 1];
        }
        const float p0 = b0 + b1, p1 = c0 + c1;

        float* slot = slots + ((size_t)(t & 1) * KWG + g) * NN;
        __hip_atomic_store(&slot[n0], p0, __ATOMIC_RELAXED, __HIP_MEMORY_SCOPE_AGENT);
        __hip_atomic_store(&slot[n1], p1, __ATOMIC_RELAXED, __HIP_MEMORY_SCOPE_AGENT);
        __syncthreads();   // each wave drains vmcnt before barrier -> stores at LLC

        if (tid == 0)
            __hip_atomic_store(&flags[g * 16], (unsigned)(t + 1),
                               __ATOMIC_RELEASE, __HIP_MEMORY_SCOPE_AGENT);

        if (wave == 0 && lane < KWG) {
            while (__hip_atomic_load(&flags[lane * 16], __ATOMIC_RELAXED,
                                     __HIP_MEMORY_SCOPE_AGENT) <= (unsigned)t) {}
        }
        __syncthreads();

        // ---- gather all partials, finish the step (redundant in every WG)
        const float* sl = slots + (size_t)(t & 1) * KWG * NN;
        float s0 = 0.f, s1 = 0.f;
#pragma unroll
        for (int gg = 0; gg < KWG; ++gg) {
            s0 += __hip_atomic_load(&sl[gg * NN + n0], __ATOMIC_RELAXED, __HIP_MEMORY_SCOPE_AGENT);
            s1 += __hip_atomic_load(&sl[gg * NN + n1], __ATOMIC_RELAXED, __HIP_MEMORY_SCOPE_AGENT);
        }
        const float h0n = tanhf(xt0 + s0 + hB0);
        const float h1n = tanhf(xt1 + s1 + hB1);
        hsh[n0] = h0n;
        hsh[n1] = h1n;
        if ((n0 >> 5) == g) out[(size_t)t * NN + n0] = h0n;
        if ((n1 >> 5) == g) out[(size_t)t * NN + n1] = h1n;
        __syncthreads();   // protect hsh reads of next iteration
    }
}

extern "C" void kernel_launch(void* const* d_in, const int* in_sizes, int n_in,
                              void* d_out, int out_size, void* d_ws, size_t ws_size,
                              hipStream_t stream) {
    const float* x   = (const float*)d_in[0];
    const float* Wx  = (const float*)d_in[1];
    const float* bx  = (const float*)d_in[2];
    // d_in[3]=Wu, d_in[4]=bu unused: update gate cancels in the reference
    const float* Wr  = (const float*)d_in[5];
    const float* br  = (const float*)d_in[6];
    const float* hW  = (const float*)d_in[7];
    // d_in[8]=hUW unused
    const float* hRW = (const float*)d_in[9];
    const float* hB  = (const float*)d_in[10];
    // d_in[11]=hUB unused
    const float* hRB = (const float*)d_in[12];
    const float* h0  = (const float*)d_in[13];
    float* out = (float*)d_out;

    char* ws = (char*)d_ws;
    float* xT = (float*)(ws);                               // 32 MB
    float* xR = (float*)(ws + 33554432);                    // 32 MB
    float* slots = (float*)(ws + 67108864);                 // 256 KB
    unsigned int* flags = (unsigned int*)(ws + 67108864 + 262144); // 2 KB

    hipMemsetAsync(flags, 0, KWG * 16 * sizeof(unsigned int), stream);

    gemm_bias<<<dim3(16, 128), 256, 0, stream>>>(x, Wx, bx, xT);
    gemm_bias<<<dim3(16, 128), 256, 0, stream>>>(x, Wr, br, xR);

    gru_rec<<<dim3(KWG), RTHREADS, 0, stream>>>(xT, xR, hRW, hW, hRB, hB, h0,
                                                out, slots, flags);
}

// Round 2
// 33067.349 us; speedup vs baseline: 1.0204x; 1.0204x over previous
//
#include <hip/hip_runtime.h>
#include <hip/hip_bf16.h>
#include <math.h>

#define T_STEPS 8192
#define NN      1024
#define KWG     32      // persistent workgroups in recurrent kernel
#define RT      512

__device__ __forceinline__ float fast_sigmoid(float z) {
    z = fminf(fmaxf(z, -30.f), 30.f);
    return 1.f / (1.f + __expf(-z));
}
__device__ __forceinline__ float fast_tanh(float x) {
    x = fminf(fmaxf(x, -9.f), 9.f);
    const float e = __expf(2.f * x);
    return (e - 1.f) / (e + 1.f);
}

// ---------------- GEMM: C[8192,1024] = A[8192,1024] @ W[1024,1024] + bias ----
__global__ __launch_bounds__(256) void gemm_bias(
    const float* __restrict__ A, const float* __restrict__ W,
    const float* __restrict__ bias, float* __restrict__ C)
{
    const int bn = blockIdx.x;   // 0..15 (N tiles of 64)
    const int bm = blockIdx.y;   // 0..127 (M tiles of 64)
    const int tid = threadIdx.x;

    __shared__ __align__(16) float As[16][68];   // pad 64->68: kills 4-way store conflicts
    __shared__ __align__(16) float Bs[16][68];

    const int row0 = bm * 64, col0 = bn * 64;
    const int tm = (tid >> 4) << 2;   // 0..60
    const int tn = (tid & 15) << 2;   // 0..60

    float acc[4][4] = {};

    for (int k0 = 0; k0 < 1024; k0 += 16) {
        {
            const int m = tid >> 2, kq = (tid & 3) << 2;
            const float4 v = *reinterpret_cast<const float4*>(&A[(size_t)(row0 + m) * 1024 + k0 + kq]);
            As[kq + 0][m] = v.x; As[kq + 1][m] = v.y; As[kq + 2][m] = v.z; As[kq + 3][m] = v.w;
            const int kk = tid >> 4, nq = (tid & 15) << 2;
            *reinterpret_cast<float4*>(&Bs[kk][nq]) =
                *reinterpret_cast<const float4*>(&W[(size_t)(k0 + kk) * 1024 + col0 + nq]);
        }
        __syncthreads();
#pragma unroll
        for (int k = 0; k < 16; ++k) {
            const float4 a4 = *reinterpret_cast<const float4*>(&As[k][tm]);
            const float4 b4 = *reinterpret_cast<const float4*>(&Bs[k][tn]);
            const float a[4] = {a4.x, a4.y, a4.z, a4.w};
            const float b[4] = {b4.x, b4.y, b4.z, b4.w};
#pragma unroll
            for (int i = 0; i < 4; ++i)
#pragma unroll
                for (int j = 0; j < 4; ++j) acc[i][j] += a[i] * b[j];
        }
        __syncthreads();
    }
#pragma unroll
    for (int i = 0; i < 4; ++i)
#pragma unroll
        for (int j = 0; j < 4; ++j)
            C[(size_t)(row0 + tm + i) * 1024 + col0 + tn + j] = acc[i][j] + bias[col0 + tn + j];
}

// ---------------- Recurrent scan -------------------------------------------
// 32 persistent WGs, weights in VGPRs, h replicated per-WG in LDS.
// Exchange = u64 atomicAdd of (1<<38) + fixed_point(partial): the count field
// in the value IS the completion flag, so one poll of your own slot replaces
// {drain, flag, poll, gather}. Double-buffered, never zeroed (prev tracked in
// regs); integer adds make the cross-WG reduction bit-deterministic.
__global__ __launch_bounds__(RT, 2) void gru_rec(
    const float* __restrict__ xT, const float* __restrict__ xR,
    const float* __restrict__ hRW, const float* __restrict__ hW,
    const float* __restrict__ hRB, const float* __restrict__ hB,
    const float* __restrict__ h0, float* __restrict__ out,
    unsigned long long* __restrict__ slots)   // [2][NN] u64
{
    const int g = blockIdx.x;        // 0..31
    const int tid = threadIdx.x;     // 0..511
    const int lane = tid & 63;
    const int wave = tid >> 6;       // 0..7

    __shared__ __align__(16) float hsh[1088];  // 64-chunk c at c*68 (2-way max)
    __shared__ __align__(16) float rh[32];

    // phase 1: column j (of this WG's 32), 16 lanes (c) split the i range
    const int j = (wave << 2) | (lane >> 4);   // 0..31
    const int c = lane & 15;                   // i-chunk: [c*64, c*64+64)
    const bool leader = (c == 0);

    float w1[64];
#pragma unroll
    for (int k = 0; k < 64; ++k)
        w1[k] = hRW[(size_t)(c * 64 + k) * NN + g * 32 + j];

    // phase 2: thread owns outputs n0, n1
    const int n0 = tid, n1 = tid + RT;
    const int pi0 = n0 + (n0 >> 6) * 4, pi1 = n1 + (n1 >> 6) * 4;
    float w2a[32], w2b[32];
#pragma unroll
    for (int k = 0; k < 32; ++k) {
        w2a[k] = hW[(size_t)(g * 32 + k) * NN + n0];
        w2b[k] = hW[(size_t)(g * 32 + k) * NN + n1];
    }
    const float hB0 = hB[n0], hB1 = hB[n1];
    const int mj = g * 32 + j;
    const int pij = mj + (mj >> 6) * 4;
    const float hRBj = leader ? hRB[mj] : 0.f;
    const bool own0 = ((n0 >> 5) == g), own1 = ((n1 >> 5) == g);

    hsh[pi0] = h0[n0];
    hsh[pi1] = h0[n1];
    __syncthreads();

    float hp0 = 0.f, hp1 = 0.f;                       // h from previous step
    unsigned long long pA0 = 0, pA1 = 0, pB0 = 0, pB1 = 0;  // prev slot values
    unsigned long long tgA = 0, tgB = 0;              // cumulative count targets
    const float SC = 1048576.f, ISC = 1.f / 1048576.f;

#define GRU_STEP(T_, SL_, PV0_, PV1_, TG_) do { \
    const float xt0 = xT[(size_t)(T_) * NN + n0]; \
    const float xt1 = xT[(size_t)(T_) * NN + n1]; \
    float xr = 0.f; \
    if (leader) xr = xR[(size_t)(T_) * NN + mj]; \
    if ((T_) > 0) {  /* staggered: store h(t-1); ack hides under this step */ \
        if (own0) out[(size_t)((T_) - 1) * NN + n0] = hp0; \
        if (own1) out[(size_t)((T_) - 1) * NN + n1] = hp1; \
    } \
    float a0 = 0.f, a1 = 0.f, a2 = 0.f, a3 = 0.f; \
    _Pragma("unroll") \
    for (int k = 0; k < 64; k += 4) { \
        const float4 hv = *reinterpret_cast<const float4*>(&hsh[c * 68 + k]); \
        a0 += hv.x * w1[k + 0]; a1 += hv.y * w1[k + 1]; \
        a2 += hv.z * w1[k + 2]; a3 += hv.w * w1[k + 3]; \
    } \
    float s = (a0 + a1) + (a2 + a3); \
    s += __shfl_xor(s, 1); s += __shfl_xor(s, 2); \
    s += __shfl_xor(s, 4); s += __shfl_xor(s, 8); \
    if (leader) rh[j] = fast_sigmoid(xr + hRBj + s) * hsh[pij]; \
    __syncthreads(); \
    float b0 = 0.f, b1 = 0.f, d0 = 0.f, d1 = 0.f; \
    _Pragma("unroll") \
    for (int k = 0; k < 32; k += 2) { \
        const float2 rv = *reinterpret_cast<const float2*>(&rh[k]); \
        b0 += rv.x * w2a[k]; b1 += rv.y * w2a[k + 1]; \
        d0 += rv.x * w2b[k]; d1 += rv.y * w2b[k + 1]; \
    } \
    const unsigned long long q0 = (1ULL << 38) + \
        (unsigned long long)(long long)llrintf((b0 + b1) * SC); \
    const unsigned long long q1 = (1ULL << 38) + \
        (unsigned long long)(long long)llrintf((d0 + d1) * SC); \
    __hip_atomic_fetch_add(&(SL_)[n0], q0, __ATOMIC_RELAXED, __HIP_MEMORY_SCOPE_AGENT); \
    __hip_atomic_fetch_add(&(SL_)[n1], q1, __ATOMIC_RELAXED, __HIP_MEMORY_SCOPE_AGENT); \
    TG_ += (unsigned long long)KWG << 38; \
    const long long thr = (long long)TG_ - (1LL << 36); \
    unsigned long long v0 = 0, v1 = 0; \
    bool f0 = false, f1 = false; \
    do { \
        if (!f0) { v0 = __hip_atomic_load(&(SL_)[n0], __ATOMIC_RELAXED, __HIP_MEMORY_SCOPE_AGENT); \
                   f0 = ((long long)v0 >= thr); } \
        if (!f1) { v1 = __hip_atomic_load(&(SL_)[n1], __ATOMIC_RELAXED, __HIP_MEMORY_SCOPE_AGENT); \
                   f1 = ((long long)v1 >= thr); } \
    } while (!(f0 && f1)); \
    const float s0 = (float)(long long)(v0 - PV0_ - ((unsigned long long)KWG << 38)) * ISC; \
    const float s1 = (float)(long long)(v1 - PV1_ - ((unsigned long long)KWG << 38)) * ISC; \
    PV0_ = v0; PV1_ = v1; \
    hp0 = fast_tanh(xt0 + s0 + hB0); \
    hp1 = fast_tanh(xt1 + s1 + hB1); \
    hsh[pi0] = hp0; hsh[pi1] = hp1; \
    __syncthreads(); \
} while (0)

    for (int t = 0; t < T_STEPS; t += 2) {
        GRU_STEP(t,     slots,      pA0, pA1, tgA);
        GRU_STEP(t + 1, slots + NN, pB0, pB1, tgB);
    }
#undef GRU_STEP
    if (own0) out[(size_t)(T_STEPS - 1) * NN + n0] = hp0;
    if (own1) out[(size_t)(T_STEPS - 1) * NN + n1] = hp1;
}

extern "C" void kernel_launch(void* const* d_in, const int* in_sizes, int n_in,
                              void* d_out, int out_size, void* d_ws, size_t ws_size,
                              hipStream_t stream) {
    const float* x   = (const float*)d_in[0];
    const float* Wx  = (const float*)d_in[1];
    const float* bx  = (const float*)d_in[2];
    // d_in[3]=Wu, d_in[4]=bu unused: update gate cancels in the reference
    const float* Wr  = (const float*)d_in[5];
    const float* br  = (const float*)d_in[6];
    const float* hW  = (const float*)d_in[7];
    // d_in[8]=hUW unused
    const float* hRW = (const float*)d_in[9];
    const float* hB  = (const float*)d_in[10];
    // d_in[11]=hUB unused
    const float* hRB = (const float*)d_in[12];
    const float* h0  = (const float*)d_in[13];
    float* out = (float*)d_out;

    char* ws = (char*)d_ws;
    float* xT = (float*)(ws);                               // 32 MB
    float* xR = (float*)(ws + 33554432);                    // 32 MB
    unsigned long long* slots = (unsigned long long*)(ws + 67108864); // 16 KB

    hipMemsetAsync(slots, 0, 2 * NN * sizeof(unsigned long long), stream);

    gemm_bias<<<dim3(16, 128), 256, 0, stream>>>(x, Wx, bx, xT);
    gemm_bias<<<dim3(16, 128), 256, 0, stream>>>(x, Wr, br, xR);

    gru_rec<<<dim3(KWG), RT, 0, stream>>>(xT, xR, hRW, hW, hRB, hB, h0,
                                          out, slots);
}

// Round 3
// 32731.958 us; speedup vs baseline: 1.0309x; 1.0102x over previous
//
#include <hip/hip_runtime.h>
#include <hip/hip_bf16.h>
#include <math.h>

#define T_STEPS 8192
#define NN      1024
#define KWG     32      // persistent workgroups in recurrent kernel
#define RT      512

__device__ __forceinline__ float fast_sigmoid(float z) {
    z = fminf(fmaxf(z, -30.f), 30.f);
    return 1.f / (1.f + __expf(-z));
}
__device__ __forceinline__ float fast_tanh(float x) {
    x = fminf(fmaxf(x, -9.f), 9.f);
    const float e = __expf(2.f * x);
    return (e - 1.f) / (e + 1.f);
}

// ---------------- GEMM: C[8192,1024] = A[8192,1024] @ W[1024,1024] + bias ----
__global__ __launch_bounds__(256) void gemm_bias(
    const float* __restrict__ A, const float* __restrict__ W,
    const float* __restrict__ bias, float* __restrict__ C)
{
    const int bn = blockIdx.x;   // 0..15 (N tiles of 64)
    const int bm = blockIdx.y;   // 0..127 (M tiles of 64)
    const int tid = threadIdx.x;

    __shared__ __align__(16) float As[16][68];
    __shared__ __align__(16) float Bs[16][68];

    const int row0 = bm * 64, col0 = bn * 64;
    const int tm = (tid >> 4) << 2;
    const int tn = (tid & 15) << 2;

    float acc[4][4] = {};

    for (int k0 = 0; k0 < 1024; k0 += 16) {
        {
            const int m = tid >> 2, kq = (tid & 3) << 2;
            const float4 v = *reinterpret_cast<const float4*>(&A[(size_t)(row0 + m) * 1024 + k0 + kq]);
            As[kq + 0][m] = v.x; As[kq + 1][m] = v.y; As[kq + 2][m] = v.z; As[kq + 3][m] = v.w;
            const int kk = tid >> 4, nq = (tid & 15) << 2;
            *reinterpret_cast<float4*>(&Bs[kk][nq]) =
                *reinterpret_cast<const float4*>(&W[(size_t)(k0 + kk) * 1024 + col0 + nq]);
        }
        __syncthreads();
#pragma unroll
        for (int k = 0; k < 16; ++k) {
            const float4 a4 = *reinterpret_cast<const float4*>(&As[k][tm]);
            const float4 b4 = *reinterpret_cast<const float4*>(&Bs[k][tn]);
            const float a[4] = {a4.x, a4.y, a4.z, a4.w};
            const float b[4] = {b4.x, b4.y, b4.z, b4.w};
#pragma unroll
            for (int i = 0; i < 4; ++i)
#pragma unroll
                for (int j = 0; j < 4; ++j) acc[i][j] += a[i] * b[j];
        }
        __syncthreads();
    }
#pragma unroll
    for (int i = 0; i < 4; ++i)
#pragma unroll
        for (int j = 0; j < 4; ++j)
            C[(size_t)(row0 + tm + i) * 1024 + col0 + tn + j] = acc[i][j] + bias[col0 + tn + j];
}

// ---------------- Recurrent scan: 2-RT owner-reduce exchange ----------------
// RT1: each WG plain-stores tagged rank-32 partials to its own region; the
//      OWNER WG of column n polls the 32 partials (one poller per slot),
//      reduces, tanh, writes out + broadcasts tagged h.
// RT2: everyone polls the tagged h broadcast. No atomics anywhere; tags
//      (step+1 in high 32 bits, f32 bits low) double-buffer without zeroing.
__global__ __launch_bounds__(RT, 1) void gru_rec(
    const float* __restrict__ xT, const float* __restrict__ xR,
    const float* __restrict__ hRW, const float* __restrict__ hW,
    const float* __restrict__ hRB, const float* __restrict__ hB,
    const float* __restrict__ h0, float* __restrict__ out,
    unsigned long long* __restrict__ P,     // [2][KWG][NN]
    unsigned long long* __restrict__ hbc)   // [2][NN]
{
    const int g = blockIdx.x;        // 0..31
    const int tid = threadIdx.x;     // 0..511
    const int lane = tid & 63;
    const int wave = tid >> 6;

    __shared__ __align__(16) float hsh[1088];  // 64-chunk c at c*68
    __shared__ __align__(16) float rh[32];

    // phase 1: own column j (0..31), 16 lanes (c) split i into 64-chunks
    const int j = (wave << 2) | (lane >> 4);
    const int c = lane & 15;
    const bool leader1 = (c == 0);
    float w1[64];
#pragma unroll
    for (int k = 0; k < 64; ++k)
        w1[k] = hRW[(size_t)(c * 64 + k) * NN + g * 32 + j];

    // phase 2: thread owns outputs n0, n1
    const int n0 = tid, n1 = tid + RT;
    const int pi0 = n0 + (n0 >> 6) * 4, pi1 = n1 + (n1 >> 6) * 4;
    float w2a[32], w2b[32];
#pragma unroll
    for (int k = 0; k < 32; ++k) {
        w2a[k] = hW[(size_t)(g * 32 + k) * NN + n0];
        w2b[k] = hW[(size_t)(g * 32 + k) * NN + n1];
    }

    // owner-reduce mapping: column jj (0..31) x 16 reducer lanes (cc)
    const int jj = tid >> 4, cc = tid & 15;
    const bool eleader = (cc == 0);
    const int mjj = g * 32 + jj;
    const float hBo = hB[mjj];

    const int mj = g * 32 + j;
    const int pij = mj + (mj >> 6) * 4;
    const float hRBj = hRB[mj];

    hsh[pi0] = h0[n0];
    hsh[pi1] = h0[n1];
    __syncthreads();

    for (int t = 0; t < T_STEPS; ++t) {
        const unsigned tag = (unsigned)(t + 1);
        unsigned long long* __restrict__ Pb = P + (size_t)(t & 1) * KWG * NN;
        unsigned long long* __restrict__ Hb = hbc + (size_t)(t & 1) * NN;

        // prefetch inputs consumed later in the step
        float xr = 0.f, xto = 0.f;
        if (leader1) xr  = xR[(size_t)t * NN + mj];
        if (eleader) xto = xT[(size_t)t * NN + mjj];

        // ---- phase 1: r-gemv partials over own 64-chunk
        float a0 = 0.f, a1 = 0.f, a2 = 0.f, a3 = 0.f;
#pragma unroll
        for (int k = 0; k < 64; k += 4) {
            const float4 hv = *reinterpret_cast<const float4*>(&hsh[c * 68 + k]);
            a0 += hv.x * w1[k + 0]; a1 += hv.y * w1[k + 1];
            a2 += hv.z * w1[k + 2]; a3 += hv.w * w1[k + 3];
        }
        float s = (a0 + a1) + (a2 + a3);
        s += __shfl_xor(s, 1); s += __shfl_xor(s, 2);
        s += __shfl_xor(s, 4); s += __shfl_xor(s, 8);
        if (leader1) rh[j] = fast_sigmoid(xr + hRBj + s) * hsh[pij];
        __syncthreads();

        // ---- phase 2: rank-32 partials for n0, n1; tagged plain stores
        float b0 = 0.f, b1 = 0.f, d0 = 0.f, d1 = 0.f;
#pragma unroll
        for (int k = 0; k < 32; k += 2) {
            const float2 rv = *reinterpret_cast<const float2*>(&rh[k]);
            b0 += rv.x * w2a[k]; b1 += rv.y * w2a[k + 1];
            d0 += rv.x * w2b[k]; d1 += rv.y * w2b[k + 1];
        }
        const unsigned long long q0 =
            ((unsigned long long)tag << 32) | (unsigned)__float_as_uint(b0 + b1);
        const unsigned long long q1 =
            ((unsigned long long)tag << 32) | (unsigned)__float_as_uint(d0 + d1);
        __hip_atomic_store(&Pb[(size_t)g * NN + n0], q0, __ATOMIC_RELAXED, __HIP_MEMORY_SCOPE_AGENT);
        __hip_atomic_store(&Pb[(size_t)g * NN + n1], q1, __ATOMIC_RELAXED, __HIP_MEMORY_SCOPE_AGENT);

        // ---- RT1: owner-reduce — poll partials from regions cc and cc+16
        {
            unsigned long long va = 0, vb = 0;
            bool fa = false, fb = false;
            do {
                if (!fa) { va = __hip_atomic_load(&Pb[(size_t)cc * NN + mjj],
                             __ATOMIC_RELAXED, __HIP_MEMORY_SCOPE_AGENT);
                           fa = ((unsigned)(va >> 32) == tag); }
                if (!fb) { vb = __hip_atomic_load(&Pb[(size_t)(cc + 16) * NN + mjj],
                             __ATOMIC_RELAXED, __HIP_MEMORY_SCOPE_AGENT);
                           fb = ((unsigned)(vb >> 32) == tag); }
            } while (!(fa && fb));
            float s2 = __uint_as_float((unsigned)va) + __uint_as_float((unsigned)vb);
            s2 += __shfl_xor(s2, 1); s2 += __shfl_xor(s2, 2);
            s2 += __shfl_xor(s2, 4); s2 += __shfl_xor(s2, 8);
            if (eleader) {
                const float hn = fast_tanh(xto + s2 + hBo);
                out[(size_t)t * NN + mjj] = hn;
                __hip_atomic_store(&Hb[mjj],
                    ((unsigned long long)tag << 32) | (unsigned)__float_as_uint(hn),
                    __ATOMIC_RELAXED, __HIP_MEMORY_SCOPE_AGENT);
            }
        }

        // ---- RT2: poll h broadcast, refill LDS h
        {
            unsigned long long ua = 0, ub = 0;
            bool fa = false, fb = false;
            do {
                if (!fa) { ua = __hip_atomic_load(&Hb[n0], __ATOMIC_RELAXED,
                             __HIP_MEMORY_SCOPE_AGENT);
                           fa = ((unsigned)(ua >> 32) == tag); }
                if (!fb) { ub = __hip_atomic_load(&Hb[n1], __ATOMIC_RELAXED,
                             __HIP_MEMORY_SCOPE_AGENT);
                           fb = ((unsigned)(ub >> 32) == tag); }
            } while (!(fa && fb));
            hsh[pi0] = __uint_as_float((unsigned)ua);
            hsh[pi1] = __uint_as_float((unsigned)ub);
        }
        __syncthreads();
    }
}

extern "C" void kernel_launch(void* const* d_in, const int* in_sizes, int n_in,
                              void* d_out, int out_size, void* d_ws, size_t ws_size,
                              hipStream_t stream) {
    const float* x   = (const float*)d_in[0];
    const float* Wx  = (const float*)d_in[1];
    const float* bx  = (const float*)d_in[2];
    // d_in[3]=Wu, d_in[4]=bu unused: update gate cancels in the reference
    const float* Wr  = (const float*)d_in[5];
    const float* br  = (const float*)d_in[6];
    const float* hW  = (const float*)d_in[7];
    // d_in[8]=hUW unused
    const float* hRW = (const float*)d_in[9];
    const float* hB  = (const float*)d_in[10];
    // d_in[11]=hUB unused
    const float* hRB = (const float*)d_in[12];
    const float* h0  = (const float*)d_in[13];
    float* out = (float*)d_out;

    char* ws = (char*)d_ws;
    float* xT = (float*)(ws);                               // 32 MB
    float* xR = (float*)(ws + 33554432);                    // 32 MB
    unsigned long long* P   = (unsigned long long*)(ws + 67108864);          // 512 KB
    unsigned long long* hbc = (unsigned long long*)(ws + 67108864 + 524288); // 16 KB

    // clear tags (stale tags from a previous graph replay would collide)
    hipMemsetAsync(P, 0, (2 * KWG * NN + 2 * NN) * sizeof(unsigned long long), stream);

    gemm_bias<<<dim3(16, 128), 256, 0, stream>>>(x, Wx, bx, xT);
    gemm_bias<<<dim3(16, 128), 256, 0, stream>>>(x, Wr, br, xR);

    gru_rec<<<dim3(KWG), RT, 0, stream>>>(xT, xR, hRW, hW, hRB, hB, h0,
                                          out, P, hbc);
}